// Round 1
// baseline (1267.225 us; speedup 1.0000x reference)
//
#include <hip/hip_runtime.h>

// Problem: BiLSTM-CRF tagger NLL (forward only).
// B=64, L=128, E=300, H=256 (per dir), 4H=1024, T=64, V=50000.
// Output: single f32 scalar = mean(log_z - numerator).
//
// ws layout (float units):
//   XP_OFF   = 0          : xp[2][8192][1024]   (input projections, biases folded)
//   LSTM_OFF = 16777216    : lstm_out[8192][512] (cols 0-255 fwd h, 256-511 bwd h)
//   EM_OFF   = 20971520    : emissions[8192][64]
//   WBF_OFF  = 21495808    : w_hh bf16 repacked, 2*128*256*8 ushorts (1 MB)
//   NLL_OFF  = 21757952    : per-batch nll [64]
//   total = 21758016 floats = 87,032,064 bytes

#define XP_OFF   0
#define LSTM_OFF 16777216
#define EM_OFF   20971520
#define WBF_OFF  21495808
#define NLL_OFF  21757952

__device__ __forceinline__ unsigned short f2bf(float f) {
    unsigned u = __float_as_uint(f);
    unsigned r = (u + 0x7fffu + ((u >> 16) & 1u)) >> 16;
    return (unsigned short)r;
}
__device__ __forceinline__ float bflo(unsigned u) { return __uint_as_float(u << 16); }
__device__ __forceinline__ float bfhi(unsigned u) { return __uint_as_float(u & 0xffff0000u); }
__device__ __forceinline__ float sigmf(float x) { return 1.f / (1.f + __expf(-x)); }
__device__ __forceinline__ float tanhfast(float x) {
    float t = __expf(2.f * x);
    return 1.f - 2.f / (t + 1.f);
}

// ---------------- K0: repack w_hh (f32 -> bf16) ----------------
// Layout: dword index d = ((dir*128 + k2)*256 + j)*4 + g
//   dword = bf16(w[g*256+j][2*k2]) | bf16(w[g*256+j][2*k2+1]) << 16
__global__ __launch_bounds__(256) void cvt_whh(
    const float* __restrict__ wf, const float* __restrict__ wb,
    unsigned int* __restrict__ out)
{
    int d = blockIdx.x * 256 + threadIdx.x;   // 0 .. 262143
    int g   = d & 3;
    int j   = (d >> 2) & 255;
    int k2  = (d >> 10) & 127;
    int dir = d >> 17;
    const float* w = dir ? wb : wf;
    int row = g * 256 + j;
    float lo = w[(size_t)row * 256 + 2 * k2];
    float hi = w[(size_t)row * 256 + 2 * k2 + 1];
    out[d] = (unsigned)f2bf(lo) | ((unsigned)f2bf(hi) << 16);
}

// ---------------- K1: fused gather + input projection GEMM ----------------
// xp[dir][m][n] = emb[sent[m]] . w_ih_dir[n] + b_ih[n] + b_hh[n]
// M=8192, N=2048 (2 dirs x 1024), K=300.  BM=BN=128, BK=60.
__global__ __launch_bounds__(256) void xp_gemm(
    const int* __restrict__ sent, const float* __restrict__ emb,
    const float* __restrict__ w_ih_f, const float* __restrict__ b_ih_f, const float* __restrict__ b_hh_f,
    const float* __restrict__ w_ih_b, const float* __restrict__ b_ih_b, const float* __restrict__ b_hh_b,
    float* __restrict__ xp)
{
    __shared__ float as[60][128];
    __shared__ float bs[60][128];
    __shared__ int sidx[128];
    const int tid = threadIdx.x;
    const int m0 = blockIdx.x * 128;
    const int nt = blockIdx.y;
    const int dir = nt >> 3;
    const int n0 = (nt & 7) * 128;
    const float* w_ih = dir ? w_ih_b : w_ih_f;
    const float* bi = dir ? b_ih_b : b_ih_f;
    const float* bh = dir ? b_hh_b : b_hh_f;
    if (tid < 128) sidx[tid] = sent[m0 + tid];
    __syncthreads();
    const int lr = tid >> 1;          // 0..127 tile row
    const int lh = tid & 1;           // k half (30 each)
    const int rb = (tid & 15) * 4;    // micro rows: rb..rb+3, 64+rb..64+rb+3
    const int cb = (tid >> 4) * 4;    // micro cols: cb..cb+3, 64+cb..64+cb+3
    float acc[8][8] = {};
    const float* asrc = emb  + (size_t)sidx[lr] * 300 + lh * 30;
    const float* bsrc = w_ih + (size_t)(n0 + lr) * 300 + lh * 30;
    for (int kc = 0; kc < 5; ++kc) {
        #pragma unroll
        for (int i = 0; i < 15; ++i) {
            float2 va = *(const float2*)(asrc + 2 * i);
            as[lh * 30 + 2 * i][lr]     = va.x;
            as[lh * 30 + 2 * i + 1][lr] = va.y;
            float2 vb = *(const float2*)(bsrc + 2 * i);
            bs[lh * 30 + 2 * i][lr]     = vb.x;
            bs[lh * 30 + 2 * i + 1][lr] = vb.y;
        }
        asrc += 60; bsrc += 60;
        __syncthreads();
        #pragma unroll 4
        for (int kk = 0; kk < 60; ++kk) {
            float a[8], b[8];
            *(float4*)(a)     = *(const float4*)&as[kk][rb];
            *(float4*)(a + 4) = *(const float4*)&as[kk][64 + rb];
            *(float4*)(b)     = *(const float4*)&bs[kk][cb];
            *(float4*)(b + 4) = *(const float4*)&bs[kk][64 + cb];
            #pragma unroll
            for (int i = 0; i < 8; ++i)
                #pragma unroll
                for (int jj = 0; jj < 8; ++jj)
                    acc[i][jj] += a[i] * b[jj];
        }
        __syncthreads();
    }
    float bias[8];
    #pragma unroll
    for (int jj = 0; jj < 4; ++jj) {
        bias[jj]     = bi[n0 + cb + jj]      + bh[n0 + cb + jj];
        bias[4 + jj] = bi[n0 + 64 + cb + jj] + bh[n0 + 64 + cb + jj];
    }
    float* outp = xp + (size_t)dir * 8388608 + (size_t)m0 * 1024 + n0;
    #pragma unroll
    for (int i = 0; i < 8; ++i) {
        int r = (i < 4) ? (rb + i) : (64 + rb + i - 4);
        float4 o0 = make_float4(acc[i][0] + bias[0], acc[i][1] + bias[1],
                                acc[i][2] + bias[2], acc[i][3] + bias[3]);
        float4 o1 = make_float4(acc[i][4] + bias[4], acc[i][5] + bias[5],
                                acc[i][6] + bias[6], acc[i][7] + bias[7]);
        *(float4*)&outp[(size_t)r * 1024 + cb]      = o0;
        *(float4*)&outp[(size_t)r * 1024 + 64 + cb] = o1;
    }
}

// ---------------- K2: LSTM recurrence (both dirs) ----------------
// 128 blocks = (dir, batch). 256 threads: thread j owns hidden unit j
// (gate rows j, 256+j, 512+j, 768+j). h double-buffered in LDS.
__global__ __launch_bounds__(256) void lstm_rec(
    const float* __restrict__ xp, const uint4* __restrict__ wbf,
    float* __restrict__ lstm_out)
{
    const int bid = blockIdx.x;
    const int dir = bid >> 6;
    const int b = bid & 63;
    const int j = threadIdx.x;
    __shared__ float hbuf[2][256];
    hbuf[0][j] = 0.f;
    float c = 0.f;
    const float* xpb = xp + (size_t)dir * 8388608 + (size_t)b * 131072;
    const uint4* wbp = wbf + (size_t)dir * 32768 + j;
    __syncthreads();
    int p = 0;
    for (int s = 0; s < 128; ++s) {
        const int l = dir ? (127 - s) : s;
        float ai = 0.f, af = 0.f, ag = 0.f, ao = 0.f;
        const float* hrow = hbuf[p];
        #pragma unroll 4
        for (int k2 = 0; k2 < 128; k2 += 2) {
            float4 h4 = *(const float4*)(hrow + 2 * k2);   // h[2k2..2k2+3], LDS broadcast
            uint4 w0 = wbp[(size_t)k2 * 256];
            uint4 w1 = wbp[(size_t)(k2 + 1) * 256];
            ai += bflo(w0.x) * h4.x + bfhi(w0.x) * h4.y;
            af += bflo(w0.y) * h4.x + bfhi(w0.y) * h4.y;
            ag += bflo(w0.z) * h4.x + bfhi(w0.z) * h4.y;
            ao += bflo(w0.w) * h4.x + bfhi(w0.w) * h4.y;
            ai += bflo(w1.x) * h4.z + bfhi(w1.x) * h4.w;
            af += bflo(w1.y) * h4.z + bfhi(w1.y) * h4.w;
            ag += bflo(w1.z) * h4.z + bfhi(w1.z) * h4.w;
            ao += bflo(w1.w) * h4.z + bfhi(w1.w) * h4.w;
        }
        const float* xr = xpb + (size_t)l * 1024;
        float gi = ai + xr[j];
        float gf = af + xr[256 + j];
        float gg = ag + xr[512 + j];
        float go = ao + xr[768 + j];
        float iv = sigmf(gi), fv = sigmf(gf), gv = tanhfast(gg), ov = sigmf(go);
        c = fv * c + iv * gv;
        float h = ov * tanhfast(c);
        lstm_out[(size_t)(b * 128 + l) * 512 + dir * 256 + j] = h;
        hbuf[p ^ 1][j] = h;
        __syncthreads();
        p ^= 1;
    }
}

// ---------------- K3: emissions GEMM ----------------
// em[m][t] = lstm_out[m] . w_out[t] + b_out[t].  M=8192, N=64, K=512.
__global__ __launch_bounds__(256) void emis_gemm(
    const float* __restrict__ lo, const float* __restrict__ w_out,
    const float* __restrict__ b_out, float* __restrict__ em)
{
    __shared__ float as[64][64];
    __shared__ float bs[64][64];
    const int tid = threadIdx.x;
    const int m0 = blockIdx.x * 64;
    const int mr = tid & 63;
    const int kq = tid >> 6;
    const int rb = (tid & 15) * 4;
    const int cb = (tid >> 4) * 4;
    float acc[4][4] = {};
    for (int kc = 0; kc < 8; ++kc) {
        const int k0 = kc * 64;
        #pragma unroll
        for (int i = 0; i < 4; ++i) {
            const int k = kq * 16 + 4 * i;
            float4 va = *(const float4*)&lo[(size_t)(m0 + mr) * 512 + k0 + k];
            as[k][mr] = va.x; as[k + 1][mr] = va.y; as[k + 2][mr] = va.z; as[k + 3][mr] = va.w;
            float4 vb = *(const float4*)&w_out[(size_t)mr * 512 + k0 + k];
            bs[k][mr] = vb.x; bs[k + 1][mr] = vb.y; bs[k + 2][mr] = vb.z; bs[k + 3][mr] = vb.w;
        }
        __syncthreads();
        #pragma unroll 8
        for (int kk = 0; kk < 64; ++kk) {
            float a[4], bb[4];
            *(float4*)a  = *(const float4*)&as[kk][rb];
            *(float4*)bb = *(const float4*)&bs[kk][cb];
            #pragma unroll
            for (int i = 0; i < 4; ++i)
                #pragma unroll
                for (int jj = 0; jj < 4; ++jj)
                    acc[i][jj] += a[i] * bb[jj];
        }
        __syncthreads();
    }
    float4 bo = *(const float4*)&b_out[cb];
    #pragma unroll
    for (int i = 0; i < 4; ++i) {
        float4 o = make_float4(acc[i][0] + bo.x, acc[i][1] + bo.y,
                               acc[i][2] + bo.z, acc[i][3] + bo.w);
        *(float4*)&em[(size_t)(m0 + rb + i) * 64 + cb] = o;
    }
}

// ---------------- K4: CRF numerator + forward algorithm ----------------
// 64 blocks (one per batch), 256 threads = 4 i-quarters x 64 tags.
__global__ __launch_bounds__(256) void crf_kernel(
    const float* __restrict__ em, const int* __restrict__ tags,
    const float* __restrict__ start_t, const float* __restrict__ end_t,
    const float* __restrict__ trans, float* __restrict__ nll)
{
    const int b = blockIdx.x;
    const int tid = threadIdx.x;
    const int j = tid & 63;
    const int q = tid >> 6;
    __shared__ float s_lds[64];
    __shared__ float part[4][64];
    __shared__ float m_sh, num_sh;
    float tr[16];
    #pragma unroll
    for (int ii = 0; ii < 16; ++ii) tr[ii] = trans[(q * 16 + ii) * 64 + j];
    const float* emb_b = em + (size_t)b * 8192;
    const int* tg_b = tags + b * 128;
    // numerator (gold path score)
    float numpart = 0.f;
    if (tid < 128) {
        int l = tid;
        int tg = tg_b[l];
        numpart = emb_b[l * 64 + tg];
        if (l < 127) numpart += trans[tg * 64 + tg_b[l + 1]];
        if (l == 0)  numpart += start_t[tg];
        if (l == 127) numpart += end_t[tg];
    }
    float red = numpart;
    #pragma unroll
    for (int off = 32; off >= 1; off >>= 1) red += __shfl_xor(red, off);
    if (j == 0) part[q][0] = red;
    if (q == 0) s_lds[j] = start_t[j] + emb_b[j];
    __syncthreads();
    if (tid == 0) num_sh = part[0][0] + part[1][0] + part[2][0] + part[3][0];
    __syncthreads();
    // forward algorithm
    for (int l = 1; l < 128; ++l) {
        if (q == 0) {
            float v = s_lds[j];
            #pragma unroll
            for (int off = 32; off >= 1; off >>= 1) v = fmaxf(v, __shfl_xor(v, off));
            if (j == 0) m_sh = v;
        }
        __syncthreads();
        const float m = m_sh;
        float sv[16];
        #pragma unroll
        for (int t4 = 0; t4 < 4; ++t4) {
            float4 v = *(const float4*)&s_lds[q * 16 + 4 * t4];
            sv[4 * t4] = v.x; sv[4 * t4 + 1] = v.y; sv[4 * t4 + 2] = v.z; sv[4 * t4 + 3] = v.w;
        }
        float acc = 0.f;
        #pragma unroll
        for (int ii = 0; ii < 16; ++ii) acc += __expf(sv[ii] + tr[ii] - m);
        part[q][j] = acc;
        __syncthreads();
        if (q == 0) {
            float t = part[0][j] + part[1][j] + part[2][j] + part[3][j];
            s_lds[j] = m + __logf(t) + emb_b[l * 64 + j];
        }
        // no trailing sync needed: next read of s_lds/part is after the
        // (a)->(b) __syncthreads, and (a) only touches thread-local s_lds[j].
    }
    if (q == 0) {
        float v = s_lds[j] + end_t[j];
        float mm = v;
        #pragma unroll
        for (int off = 32; off >= 1; off >>= 1) mm = fmaxf(mm, __shfl_xor(mm, off));
        float e = __expf(v - mm);
        #pragma unroll
        for (int off = 32; off >= 1; off >>= 1) e += __shfl_xor(e, off);
        if (j == 0) nll[b] = (mm + __logf(e)) - num_sh;
    }
}

// ---------------- K5: final mean ----------------
__global__ void finalize(const float* __restrict__ nll, float* __restrict__ out)
{
    int j = threadIdx.x;  // 64 threads
    float v = nll[j];
    #pragma unroll
    for (int off = 32; off >= 1; off >>= 1) v += __shfl_xor(v, off);
    if (j == 0) out[0] = v * (1.f / 64.f);
}

extern "C" void kernel_launch(void* const* d_in, const int* in_sizes, int n_in,
                              void* d_out, int out_size, void* d_ws, size_t ws_size,
                              hipStream_t stream) {
    const int* sent      = (const int*)d_in[0];
    const int* tags      = (const int*)d_in[1];
    const float* emb     = (const float*)d_in[2];
    const float* w_ih_f  = (const float*)d_in[3];
    const float* w_hh_f  = (const float*)d_in[4];
    const float* b_ih_f  = (const float*)d_in[5];
    const float* b_hh_f  = (const float*)d_in[6];
    const float* w_ih_b  = (const float*)d_in[7];
    const float* w_hh_b  = (const float*)d_in[8];
    const float* b_ih_b  = (const float*)d_in[9];
    const float* b_hh_b  = (const float*)d_in[10];
    const float* w_out   = (const float*)d_in[11];
    const float* b_out   = (const float*)d_in[12];
    const float* start_t = (const float*)d_in[13];
    const float* end_t   = (const float*)d_in[14];
    const float* trans   = (const float*)d_in[15];

    float* ws = (float*)d_ws;
    float* xp        = ws + XP_OFF;
    float* lstm_out  = ws + LSTM_OFF;
    float* em        = ws + EM_OFF;
    unsigned int* wbf = (unsigned int*)(ws + WBF_OFF);
    float* nll       = ws + NLL_OFF;

    cvt_whh<<<dim3(1024), dim3(256), 0, stream>>>(w_hh_f, w_hh_b, wbf);
    xp_gemm<<<dim3(64, 16), dim3(256), 0, stream>>>(sent, emb,
        w_ih_f, b_ih_f, b_hh_f, w_ih_b, b_ih_b, b_hh_b, xp);
    lstm_rec<<<dim3(128), dim3(256), 0, stream>>>(xp, (const uint4*)wbf, lstm_out);
    emis_gemm<<<dim3(128), dim3(256), 0, stream>>>(lstm_out, w_out, b_out, em);
    crf_kernel<<<dim3(64), dim3(256), 0, stream>>>(em, tags, start_t, end_t, trans, nll);
    finalize<<<dim3(1), dim3(64), 0, stream>>>(nll, (float*)d_out);
}